// Round 11
// baseline (1868.074 us; speedup 1.0000x reference)
//
#include <hip/hip_runtime.h>
#include <hip/hip_bf16.h>

typedef float f32x4 __attribute__((ext_vector_type(4)));
typedef __bf16 bf16x8 __attribute__((ext_vector_type(8)));
typedef unsigned short u16x8 __attribute__((ext_vector_type(8)));
typedef unsigned short u16;

__device__ __forceinline__ u16 f2bf(float f) {
  __bf16 h = (__bf16)f;                       // native cvt (RNE)
  return __builtin_bit_cast(u16, h);
}
__device__ __forceinline__ float bf2f(u16 s) {
  return __uint_as_float(((unsigned int)s) << 16);
}
__device__ __forceinline__ float gelu_f(float x) {
  return 0.5f * x * (1.0f + erff(x * 0.70710678118654752f)); // erf GELU
}
__device__ __forceinline__ void gload_lds16(const void* g, void* l) {
  __builtin_amdgcn_global_load_lds((const __attribute__((address_space(1))) void*)g,
                                   (__attribute__((address_space(3))) void*)l, 16, 0, 0);
}
#define MFMA(a, b, c) __builtin_amdgcn_mfma_f32_16x16x32_bf16((a), (b), (c), 0, 0, 0)
#define BARRIER_PINNED() do { \
    __builtin_amdgcn_s_barrier(); \
    asm volatile("" ::: "memory"); \
    __builtin_amdgcn_sched_barrier(0); \
  } while (0)

// ---------------- weight conversion ----------------
__global__ void cvt_all(const float* __restrict__ e1, const float* __restrict__ e2,
                        const float* __restrict__ e3, const float* __restrict__ d1,
                        const float* __restrict__ d2, const float* __restrict__ d3,
                        const float* __restrict__ mx, u16* __restrict__ dst)
{
  int i = blockIdx.x * blockDim.x + threadIdx.x;
  int stride = gridDim.x * blockDim.x;
  for (; i < 3145728; i += stride) {
    float v;
    if (i < 524288)        v = e1[i];
    else if (i < 786432)   v = e2[i - 524288];
    else if (i < 1048576)  v = e3[i - 786432];
    else if (i < 1310720)  v = d1[i - 1048576];
    else if (i < 1572864)  v = d2[i - 1310720];
    else if (i < 2097152)  v = d3[i - 1572864];
    else {
      // mix_w [L,16,16,32,32] (l,bi,j,e,d) -> W[l][o=bi*32+e][k=j*32+d]
      int j = i - 2097152;
      int l = j >> 18, rem = j & 262143;
      int o = rem >> 9, k = rem & 511;
      int bi = o >> 5, e = o & 31, jj = k >> 5, dd = k & 31;
      v = mx[(((l * 16 + bi) * 16 + jj) * 32 + e) * 32 + dd];
    }
    dst[i] = f2bf(v);
  }
}

// x f32 -> bf16 (vectorized)
__global__ void cvt_x(const float* __restrict__ s, u16* __restrict__ d) {
  int i = blockIdx.x * blockDim.x + threadIdx.x;
  int stride = gridDim.x * blockDim.x;
  for (; i < 8388608; i += stride) {          // 67108864 / 8
    float4 v0 = *(const float4*)(s + (size_t)i * 8);
    float4 v1 = *(const float4*)(s + (size_t)i * 8 + 4);
    u16x8 u;
    u[0] = f2bf(v0.x); u[1] = f2bf(v0.y); u[2] = f2bf(v0.z); u[3] = f2bf(v0.w);
    u[4] = f2bf(v1.x); u[5] = f2bf(v1.y); u[6] = f2bf(v1.z); u[7] = f2bf(v1.w);
    *(u16x8*)(d + (size_t)i * 8) = u;
  }
}

// ---------------- staging helper: one K-tile (A 128x64 + B 64x64) ----------------
__device__ __forceinline__ void stage_AB(const u16* __restrict__ Ab,
                                         const u16* __restrict__ Bb, int K,
                                         u16* At, u16* Bt, int wid, int lane)
{
  #pragma unroll
  for (int it = 0; it < 4; ++it) {
    int c = ((it * 4 + wid) << 6) + lane;     // 1024 chunks
    int row = c >> 3;
    int cb = (c & 7) << 4;
    const char* g = (const char*)(Ab + (size_t)row * K) + (cb ^ ((row & 7) << 4));
    gload_lds16(g, (char*)At + ((it * 4 + wid) << 10));
  }
  #pragma unroll
  for (int it = 0; it < 2; ++it) {
    int c = ((it * 4 + wid) << 6) + lane;     // 512 chunks
    int row = c >> 3;
    int cb = (c & 7) << 4;
    const char* g = (const char*)(Bb + (size_t)row * K) + (cb ^ ((row & 7) << 4));
    gload_lds16(g, (char*)Bt + ((it * 4 + wid) << 10));
  }
}

// ---------------- pipelined GEMM: C = A(bf16) * W^T, counted-vmcnt 3-buffer ring ----
// BM=128, BN=64, BK=64; 4 waves 2x2 (wave tile 64x32, acc[4][2]=32 VGPR).
// Depth-2 prefetch; per K-step: vmcnt(6) -> barrier -> issue kt+2 -> 16 MFMA.
// 6 gload_lds per tile per wave => vmcnt(6) == "tile kt complete" (oldest-first).
// EPI: 0 bias+GELU->bf16 ; 1 bias->bf16 ; 2 latent combine->bf16 ; 3 bias->f32
template<int EPI>
__global__ __launch_bounds__(256, 2)
void gemm_p(const u16* __restrict__ A, const u16* __restrict__ Bw,
            const float* __restrict__ bias, void* __restrict__ Cp,
            const u16* __restrict__ zOld, const float* __restrict__ scales,
            const float* __restrict__ gateBias, int M, int N, int K)
{
  __shared__ u16 At[3][128 * 64];   // 16KB each
  __shared__ u16 Bt[3][64 * 64];    // 8KB each  -> 72KB total, 2 blocks/CU
  const int tid = threadIdx.x;
  const int lane = tid & 63;
  const int wid = tid >> 6;

  // XCD-aware swizzle (ny % 8 == 0 for all shapes here)
  const int nx = N >> 6;
  const int ny = M >> 7;
  const int d = blockIdx.x;
  const int xcd = d & 7;
  const int seq = d >> 3;
  const int by = xcd * (ny >> 3) + seq / nx;
  const int bx = seq - (seq / nx) * nx;
  const int m0 = by << 7;
  const int n0 = bx << 6;

  const int wr = wid >> 1, wc = wid & 1;
  const int r16 = lane & 15;
  const int kg = (lane >> 4) << 3;
  const int sw = (r16 & 7) << 4;

  const u16* Ab = A + (size_t)m0 * K;
  const u16* Bb = Bw + (size_t)n0 * K;
  const int NT = K >> 6;

  f32x4 acc[4][2] = {};

  // prologue: issue tiles 0 and 1
  stage_AB(Ab,      Bb,      K, At[0], Bt[0], wid, lane);
  stage_AB(Ab + 64, Bb + 64, K, At[1], Bt[1], wid, lane);

  int cb = 0, ib = 2;
  for (int kt = 0; kt < NT; ++kt) {
    if (kt + 1 < NT) { asm volatile("s_waitcnt vmcnt(6)" ::: "memory"); }
    else             { asm volatile("s_waitcnt vmcnt(0)" ::: "memory"); }
    BARRIER_PINNED();

    if (kt + 2 < NT) {
      stage_AB(Ab + ((kt + 2) << 6), Bb + ((kt + 2) << 6), K, At[ib], Bt[ib], wid, lane);
      ib = (ib == 2) ? 0 : ib + 1;
    }

    const char* Ac = (const char*)At[cb];
    const char* Bc = (const char*)Bt[cb];
    #pragma unroll
    for (int kk = 0; kk < 64; kk += 32) {
      const int kb = ((kk + kg) << 1) ^ sw;
      bf16x8 av[4], bv[2];
      #pragma unroll
      for (int m = 0; m < 4; ++m)
        av[m] = *(const bf16x8*)(Ac + (wr * 64 + m * 16 + r16) * 128 + kb);
      #pragma unroll
      for (int n = 0; n < 2; ++n)
        bv[n] = *(const bf16x8*)(Bc + (wc * 32 + n * 16 + r16) * 128 + kb);
      __builtin_amdgcn_s_setprio(1);
      #pragma unroll
      for (int m = 0; m < 4; ++m)
        #pragma unroll
        for (int n = 0; n < 2; ++n)
          acc[m][n] = MFMA(av[m], bv[n], acc[m][n]);
      __builtin_amdgcn_s_setprio(0);
    }
    cb = (cb == 2) ? 0 : cb + 1;
  }

  // ---- epilogue ----  D: col = lane&15, row = (lane>>4)*4 + reg
  const int colBase = n0 + wc * 32 + r16;
  const int rowBase = m0 + wr * 64 + ((lane >> 4) << 2);
  #pragma unroll
  for (int n = 0; n < 2; ++n) {
    int col = colBase + n * 16;
    float bv_ = 0.f, gate = 0.f;
    if constexpr (EPI == 0 || EPI == 1 || EPI == 3) bv_ = bias[col];
    if constexpr (EPI == 2) gate = 1.f / (1.f + expf(-gateBias[col >> 5]));
    #pragma unroll
    for (int m = 0; m < 4; ++m) {
      #pragma unroll
      for (int r = 0; r < 4; ++r) {
        int row = rowBase + m * 16 + r;
        float v = acc[m][n][r];
        if constexpr (EPI == 0) {
          ((u16*)Cp)[(size_t)row * N + col] = f2bf(gelu_f(v + bv_));
        } else if constexpr (EPI == 1) {
          ((u16*)Cp)[(size_t)row * N + col] = f2bf(v + bv_);
        } else if constexpr (EPI == 2) {
          float sc = scales[(size_t)row * 16 + (col >> 5)];
          float zo = bf2f(zOld[(size_t)row * 512 + col]);
          ((u16*)Cp)[(size_t)row * N + col] = f2bf(zo * (1.f + sc) + gate * v);
        } else {
          ((float*)Cp)[(size_t)row * N + col] = v + bv_;
        }
      }
    }
  }
}

// ---------------- legacy enc1 (A=f32, register-staged dbuf) — ws fallback ----------
__global__ __launch_bounds__(256, 2)
void gemm_enc1_legacy(const float* __restrict__ Af, const u16* __restrict__ Bw,
                      const float* __restrict__ bias, u16* __restrict__ Cp,
                      int M, int N, int K)
{
  __shared__ u16 At[2][128 * 64];
  __shared__ u16 Bt[2][64 * 64];
  const int tid = threadIdx.x;
  const int lane = tid & 63;
  const int wid = tid >> 6;
  const int nx = N >> 6;
  const int ny = M >> 7;
  const int d = blockIdx.x;
  const int xcd = d & 7;
  const int seq = d >> 3;
  const int by = xcd * (ny >> 3) + seq / nx;
  const int bx = seq - (seq / nx) * nx;
  const int m0 = by << 7;
  const int n0 = bx << 6;
  const int wr = wid >> 1, wc = wid & 1;
  const int r16 = lane & 15;
  const int kg = (lane >> 4) << 3;
  const int sw = (r16 & 7) << 4;
  const int NT = K >> 6;
  f32x4 acc[4][2] = {};
  float4 aA[8];

  #pragma unroll
  for (int it = 0; it < 4; ++it) {
    int c = it * 256 + tid;
    int row = c >> 3;
    int cbyte = (c & 7) << 4;
    const float* src = Af + (size_t)(m0 + row) * K + ((c & 7) << 3);
    float4 v0 = *(const float4*)src;
    float4 v1 = *(const float4*)(src + 4);
    u16x8 u;
    u[0] = f2bf(v0.x); u[1] = f2bf(v0.y); u[2] = f2bf(v0.z); u[3] = f2bf(v0.w);
    u[4] = f2bf(v1.x); u[5] = f2bf(v1.y); u[6] = f2bf(v1.z); u[7] = f2bf(v1.w);
    *(u16x8*)((char*)At[0] + row * 128 + (cbyte ^ ((row & 7) << 4))) = u;
  }
  #pragma unroll
  for (int it = 0; it < 2; ++it) {
    int c = ((it * 4 + wid) << 6) + lane;
    int row = c >> 3;
    int cbyte = (c & 7) << 4;
    const char* g = (const char*)(Bw + (size_t)(n0 + row) * K) + (cbyte ^ ((row & 7) << 4));
    gload_lds16(g, (char*)Bt[0] + ((it * 4 + wid) << 10));
  }
  __syncthreads();

  for (int kt = 0; kt < NT; ++kt) {
    const int cur = kt & 1;
    const bool hasNext = (kt + 1) < NT;
    if (hasNext) {
      const int kn = (kt + 1) << 6;
      #pragma unroll
      for (int it = 0; it < 4; ++it) {
        int c = it * 256 + tid;
        int row = c >> 3;
        const float* src = Af + (size_t)(m0 + row) * K + kn + ((c & 7) << 3);
        aA[it * 2]     = *(const float4*)src;
        aA[it * 2 + 1] = *(const float4*)(src + 4);
      }
      #pragma unroll
      for (int it = 0; it < 2; ++it) {
        int c = ((it * 4 + wid) << 6) + lane;
        int row = c >> 3;
        int cbyte = (c & 7) << 4;
        const char* g = (const char*)(Bw + (size_t)(n0 + row) * K + kn) + (cbyte ^ ((row & 7) << 4));
        gload_lds16(g, (char*)Bt[cur ^ 1] + ((it * 4 + wid) << 10));
      }
    }
    #pragma unroll
    for (int kk = 0; kk < 64; kk += 32) {
      const int kb = ((kk + kg) << 1) ^ sw;
      bf16x8 av[4], bv[2];
      #pragma unroll
      for (int m = 0; m < 4; ++m)
        av[m] = *(const bf16x8*)((const char*)At[cur] + (wr * 64 + m * 16 + r16) * 128 + kb);
      #pragma unroll
      for (int n = 0; n < 2; ++n)
        bv[n] = *(const bf16x8*)((const char*)Bt[cur] + (wc * 32 + n * 16 + r16) * 128 + kb);
      #pragma unroll
      for (int m = 0; m < 4; ++m)
        #pragma unroll
        for (int n = 0; n < 2; ++n)
          acc[m][n] = MFMA(av[m], bv[n], acc[m][n]);
    }
    if (hasNext) {
      #pragma unroll
      for (int it = 0; it < 4; ++it) {
        int c = it * 256 + tid;
        int row = c >> 3;
        int cbyte = (c & 7) << 4;
        float4 v0 = aA[it * 2], v1 = aA[it * 2 + 1];
        u16x8 u;
        u[0] = f2bf(v0.x); u[1] = f2bf(v0.y); u[2] = f2bf(v0.z); u[3] = f2bf(v0.w);
        u[4] = f2bf(v1.x); u[5] = f2bf(v1.y); u[6] = f2bf(v1.z); u[7] = f2bf(v1.w);
        *(u16x8*)((char*)At[cur ^ 1] + row * 128 + (cbyte ^ ((row & 7) << 4))) = u;
      }
    }
    __syncthreads();
  }

  const int colBase = n0 + wc * 32 + r16;
  const int rowBase = m0 + wr * 64 + ((lane >> 4) << 2);
  #pragma unroll
  for (int n = 0; n < 2; ++n) {
    int col = colBase + n * 16;
    float bv_ = bias[col];
    #pragma unroll
    for (int m = 0; m < 4; ++m)
      #pragma unroll
      for (int r = 0; r < 4; ++r) {
        int row = rowBase + m * 16 + r;
        Cp[(size_t)row * N + col] = f2bf(gelu_f(acc[m][n][r] + bv_));
      }
  }
}

// ---------------- per-row bundle-norm MLP -> scales ----------------
__global__ __launch_bounds__(256)
void norm_mlp(const u16* __restrict__ z,
              const float* __restrict__ w1, const float* __restrict__ b1,
              const float* __restrict__ w2, const float* __restrict__ b2,
              const float* __restrict__ w3, float* __restrict__ scales, int Mrows)
{
  const int lane = threadIdx.x & 63;
  const int wv = threadIdx.x >> 6;
  for (int row = blockIdx.x * 4 + wv; row < Mrows; row += gridDim.x * 4) {
    u16x8 zv = *(const u16x8*)(z + (size_t)row * 512 + lane * 8);
    float ss = 0.f;
    #pragma unroll
    for (int j = 0; j < 8; ++j) { float f = bf2f(zv[j]); ss += f * f; }
    ss += __shfl_xor(ss, 1);
    ss += __shfl_xor(ss, 2);
    float nrm = sqrtf(ss) + 1e-8f;
    float h1 = b1[lane];
    #pragma unroll
    for (int i = 0; i < 16; ++i) h1 += __shfl(nrm, i * 4) * w1[lane * 16 + i];
    h1 = gelu_f(h1);
    float h2 = b2[lane];
    #pragma unroll
    for (int k = 0; k < 64; ++k) h2 += __shfl(h1, k) * w2[lane * 64 + k];
    h2 = gelu_f(h2);
    float s = 0.f;
    const int i16 = lane & 15;
    #pragma unroll
    for (int k = 0; k < 64; ++k) s += __shfl(h2, k) * w3[i16 * 64 + k];
    if (lane < 16) {
      s = (s > 20.f) ? s : log1pf(expf(s));
      scales[(size_t)row * 16 + lane] = s;
    }
  }
}

// ---------------- launch ----------------
extern "C" void kernel_launch(void* const* d_in, const int* in_sizes, int n_in,
                              void* d_out, int out_size, void* d_ws, size_t ws_size,
                              hipStream_t stream)
{
  (void)in_sizes; (void)n_in; (void)out_size;
  const float* x      = (const float*)d_in[0];
  const float* enc_w1 = (const float*)d_in[1];
  const float* enc_b1 = (const float*)d_in[2];
  const float* enc_w2 = (const float*)d_in[3];
  const float* enc_b2 = (const float*)d_in[4];
  const float* enc_w3 = (const float*)d_in[5];
  const float* enc_b3 = (const float*)d_in[6];
  const float* mlp1_w = (const float*)d_in[7];
  const float* mlp1_b = (const float*)d_in[8];
  const float* mlp2_w = (const float*)d_in[9];
  const float* mlp2_b = (const float*)d_in[10];
  const float* mlp3_w = (const float*)d_in[11];
  const float* mix_w  = (const float*)d_in[12];
  const float* gate_b = (const float*)d_in[13];
  const float* dec_w1 = (const float*)d_in[14];
  const float* dec_b1 = (const float*)d_in[15];
  const float* dec_w2 = (const float*)d_in[16];
  const float* dec_b2 = (const float*)d_in[17];
  const float* dec_w3 = (const float*)d_in[18];
  const float* dec_b3 = (const float*)d_in[19];

  char* ws = (char*)d_ws;
  const int M = 65536;
  dim3 blk(256);
  const int g512  = 8  * 512;   // (N/64)*(M/128), XCD-swizzled 1-D
  const int g1024 = 16 * 512;

  // big layout: xb 128MB | zA 64MB | (zB overlays xb) | scales | weights  = ~202 MB
  const bool bigWs = (ws_size >= 211812352ULL);
  u16 *xb, *zA, *zB;
  float* scales;
  u16* wBase;
  if (bigWs) {
    xb     = (u16*)ws;
    zA     = (u16*)(ws + 134217728ULL);
    zB     = (u16*)ws;                       // overlays xb (dead after enc1)
    scales = (float*)(ws + 201326592ULL);
    wBase  = (u16*)(ws + 205520896ULL);
  } else {
    xb     = nullptr;
    zA     = (u16*)ws;
    zB     = (u16*)(ws + 67108864ULL);
    scales = (float*)(ws + 134217728ULL);
    wBase  = (u16*)(ws + 138412032ULL);
  }
  u16* wE1 = wBase;
  u16* wE2 = wE1 + 524288;
  u16* wE3 = wE2 + 262144;
  u16* wD1 = wE3 + 262144;
  u16* wD2 = wD1 + 262144;
  u16* wD3 = wD2 + 262144;
  u16* wMix = wD3 + 524288;

  cvt_all<<<512, 256, 0, stream>>>(enc_w1, enc_w2, enc_w3, dec_w1, dec_w2, dec_w3,
                                   mix_w, wBase);

  // encoder
  if (bigWs) {
    cvt_x<<<2048, 256, 0, stream>>>(x, xb);
    gemm_p<0><<<g512, blk, 0, stream>>>(xb, wE1, enc_b1, zA, nullptr, nullptr, nullptr, M, 512, 1024);
  } else {
    gemm_enc1_legacy<<<g512, blk, 0, stream>>>(x, wE1, enc_b1, zA, M, 512, 1024);
  }
  gemm_p<0><<<g512, blk, 0, stream>>>(zA, wE2, enc_b2, zB, nullptr, nullptr, nullptr, M, 512, 512);
  gemm_p<1><<<g512, blk, 0, stream>>>(zB, wE3, enc_b3, zA, nullptr, nullptr, nullptr, M, 512, 512);

  // latent layers
  u16* cur = zA;
  u16* nxt = zB;
  for (int l = 0; l < 4; ++l) {
    norm_mlp<<<4096, dim3(256), 0, stream>>>(cur, mlp1_w + l * 1024, mlp1_b + l * 64,
                                             mlp2_w + l * 4096, mlp2_b + l * 64,
                                             mlp3_w + l * 1024, scales, M);
    gemm_p<2><<<g512, blk, 0, stream>>>(cur, wMix + (size_t)l * 262144, nullptr, nxt,
                                        cur, scales, gate_b + l * 16, M, 512, 512);
    u16* t = cur; cur = nxt; nxt = t;
  }

  // decoder
  gemm_p<0><<<g512, blk, 0, stream>>>(cur, wD1, dec_b1, nxt, nullptr, nullptr, nullptr, M, 512, 512);
  { u16* t = cur; cur = nxt; nxt = t; }
  gemm_p<0><<<g512, blk, 0, stream>>>(cur, wD2, dec_b2, nxt, nullptr, nullptr, nullptr, M, 512, 512);
  { u16* t = cur; cur = nxt; nxt = t; }
  gemm_p<3><<<g1024, blk, 0, stream>>>(cur, wD3, dec_b3, d_out, nullptr, nullptr, nullptr, M, 1024, 512);
}

// Round 12
// 1408.177 us; speedup vs baseline: 1.3266x; 1.3266x over previous
//
#include <hip/hip_runtime.h>
#include <hip/hip_bf16.h>

typedef float f32x4 __attribute__((ext_vector_type(4)));
typedef __bf16 bf16x8 __attribute__((ext_vector_type(8)));
typedef unsigned short u16x8 __attribute__((ext_vector_type(8)));
typedef unsigned short u16;

__device__ __forceinline__ u16 f2bf(float f) {
  __bf16 h = (__bf16)f;                       // native cvt (RNE)
  return __builtin_bit_cast(u16, h);
}
__device__ __forceinline__ float bf2f(u16 s) {
  return __uint_as_float(((unsigned int)s) << 16);
}
__device__ __forceinline__ float gelu_f(float x) {
  return 0.5f * x * (1.0f + erff(x * 0.70710678118654752f)); // erf GELU
}
__device__ __forceinline__ void gload_lds16(const void* g, void* l) {
  __builtin_amdgcn_global_load_lds((const __attribute__((address_space(1))) void*)g,
                                   (__attribute__((address_space(3))) void*)l, 16, 0, 0);
}
#define MFMA(a, b, c) __builtin_amdgcn_mfma_f32_16x16x32_bf16((a), (b), (c), 0, 0, 0)
#define BARRIER_PINNED() do { \
    __builtin_amdgcn_s_barrier(); \
    asm volatile("" ::: "memory"); \
    __builtin_amdgcn_sched_barrier(0); \
  } while (0)

// ---------------- weight conversion ----------------
__global__ void cvt_all(const float* __restrict__ e1, const float* __restrict__ e2,
                        const float* __restrict__ e3, const float* __restrict__ d1,
                        const float* __restrict__ d2, const float* __restrict__ d3,
                        const float* __restrict__ mx, u16* __restrict__ dst)
{
  int i = blockIdx.x * blockDim.x + threadIdx.x;
  int stride = gridDim.x * blockDim.x;
  for (; i < 3145728; i += stride) {
    float v;
    if (i < 524288)        v = e1[i];
    else if (i < 786432)   v = e2[i - 524288];
    else if (i < 1048576)  v = e3[i - 786432];
    else if (i < 1310720)  v = d1[i - 1048576];
    else if (i < 1572864)  v = d2[i - 1310720];
    else if (i < 2097152)  v = d3[i - 1572864];
    else {
      // mix_w [L,16,16,32,32] (l,bi,j,e,d) -> W[l][o=bi*32+e][k=j*32+d]
      int j = i - 2097152;
      int l = j >> 18, rem = j & 262143;
      int o = rem >> 9, k = rem & 511;
      int bi = o >> 5, e = o & 31, jj = k >> 5, dd = k & 31;
      v = mx[(((l * 16 + bi) * 16 + jj) * 32 + e) * 32 + dd];
    }
    dst[i] = f2bf(v);
  }
}

// x f32 -> bf16 (vectorized)
__global__ void cvt_x(const float* __restrict__ s, u16* __restrict__ d) {
  int i = blockIdx.x * blockDim.x + threadIdx.x;
  int stride = gridDim.x * blockDim.x;
  for (; i < 8388608; i += stride) {          // 67108864 / 8
    float4 v0 = *(const float4*)(s + (size_t)i * 8);
    float4 v1 = *(const float4*)(s + (size_t)i * 8 + 4);
    u16x8 u;
    u[0] = f2bf(v0.x); u[1] = f2bf(v0.y); u[2] = f2bf(v0.z); u[3] = f2bf(v0.w);
    u[4] = f2bf(v1.x); u[5] = f2bf(v1.y); u[6] = f2bf(v1.z); u[7] = f2bf(v1.w);
    *(u16x8*)(d + (size_t)i * 8) = u;
  }
}

// ---------------- staging helper: one K-tile (A 128x64 + B 64x64) ----------------
__device__ __forceinline__ void stage_AB(const u16* __restrict__ Ab,
                                         const u16* __restrict__ Bb, int K,
                                         u16* At, u16* Bt, int wid, int lane)
{
  #pragma unroll
  for (int it = 0; it < 4; ++it) {
    int c = ((it * 4 + wid) << 6) + lane;     // 1024 chunks
    int row = c >> 3;
    int cb = (c & 7) << 4;
    const char* g = (const char*)(Ab + (size_t)row * K) + (cb ^ ((row & 7) << 4));
    gload_lds16(g, (char*)At + ((it * 4 + wid) << 10));
  }
  #pragma unroll
  for (int it = 0; it < 2; ++it) {
    int c = ((it * 4 + wid) << 6) + lane;     // 512 chunks
    int row = c >> 3;
    int cb = (c & 7) << 4;
    const char* g = (const char*)(Bb + (size_t)row * K) + (cb ^ ((row & 7) << 4));
    gload_lds16(g, (char*)Bt + ((it * 4 + wid) << 10));
  }
}

// ---------------- pipelined GEMM: C = A(bf16) * W^T, counted-vmcnt 3-buffer ring ----
// BM=128, BN=64, BK=64; 4 waves 2x2 (wave tile 64x32, acc[4][2]=32 VGPR).
// Depth-2 prefetch; per K-step: vmcnt(6) -> barrier -> issue kt+2 -> 16 MFMA.
// EPI: 0 bias+GELU->bf16 ; 1 bias->bf16 ; 2 latent combine->bf16 ; 3 bias->f32
template<int EPI>
__global__ __launch_bounds__(256, 2)
void gemm_p(const u16* __restrict__ A, const u16* __restrict__ Bw,
            const float* __restrict__ bias, void* __restrict__ Cp,
            const u16* __restrict__ zOld, const float* __restrict__ scales,
            const float* __restrict__ gateBias, int M, int N, int K)
{
  __shared__ u16 At[3][128 * 64];   // 16KB each
  __shared__ u16 Bt[3][64 * 64];    // 8KB each  -> 72KB total, 2 blocks/CU
  const int tid = threadIdx.x;
  const int lane = tid & 63;
  const int wid = tid >> 6;

  const int nx = N >> 6;
  const int ny = M >> 7;
  const int d = blockIdx.x;
  const int xcd = d & 7;
  const int seq = d >> 3;
  const int by = xcd * (ny >> 3) + seq / nx;
  const int bx = seq - (seq / nx) * nx;
  const int m0 = by << 7;
  const int n0 = bx << 6;

  const int wr = wid >> 1, wc = wid & 1;
  const int r16 = lane & 15;
  const int kg = (lane >> 4) << 3;
  const int sw = (r16 & 7) << 4;

  const u16* Ab = A + (size_t)m0 * K;
  const u16* Bb = Bw + (size_t)n0 * K;
  const int NT = K >> 6;

  f32x4 acc[4][2] = {};

  stage_AB(Ab,      Bb,      K, At[0], Bt[0], wid, lane);
  stage_AB(Ab + 64, Bb + 64, K, At[1], Bt[1], wid, lane);

  int cb = 0, ib = 2;
  for (int kt = 0; kt < NT; ++kt) {
    if (kt + 1 < NT) { asm volatile("s_waitcnt vmcnt(6)" ::: "memory"); }
    else             { asm volatile("s_waitcnt vmcnt(0)" ::: "memory"); }
    BARRIER_PINNED();

    if (kt + 2 < NT) {
      stage_AB(Ab + ((kt + 2) << 6), Bb + ((kt + 2) << 6), K, At[ib], Bt[ib], wid, lane);
      ib = (ib == 2) ? 0 : ib + 1;
    }

    const char* Ac = (const char*)At[cb];
    const char* Bc = (const char*)Bt[cb];
    #pragma unroll
    for (int kk = 0; kk < 64; kk += 32) {
      const int kb = ((kk + kg) << 1) ^ sw;
      bf16x8 av[4], bv[2];
      #pragma unroll
      for (int m = 0; m < 4; ++m)
        av[m] = *(const bf16x8*)(Ac + (wr * 64 + m * 16 + r16) * 128 + kb);
      #pragma unroll
      for (int n = 0; n < 2; ++n)
        bv[n] = *(const bf16x8*)(Bc + (wc * 32 + n * 16 + r16) * 128 + kb);
      __builtin_amdgcn_s_setprio(1);
      #pragma unroll
      for (int m = 0; m < 4; ++m)
        #pragma unroll
        for (int n = 0; n < 2; ++n)
          acc[m][n] = MFMA(av[m], bv[n], acc[m][n]);
      __builtin_amdgcn_s_setprio(0);
    }
    cb = (cb == 2) ? 0 : cb + 1;
  }

  // ---- epilogue ----  D: col = lane&15, row = (lane>>4)*4 + reg
  const int colBase = n0 + wc * 32 + r16;
  const int rowBase = m0 + wr * 64 + ((lane >> 4) << 2);
  #pragma unroll
  for (int n = 0; n < 2; ++n) {
    int col = colBase + n * 16;
    float bv_ = 0.f, gate = 0.f;
    if constexpr (EPI == 0 || EPI == 1 || EPI == 3) bv_ = bias[col];
    if constexpr (EPI == 2) gate = 1.f / (1.f + expf(-gateBias[col >> 5]));
    #pragma unroll
    for (int m = 0; m < 4; ++m) {
      #pragma unroll
      for (int r = 0; r < 4; ++r) {
        int row = rowBase + m * 16 + r;
        float v = acc[m][n][r];
        if constexpr (EPI == 0) {
          ((u16*)Cp)[(size_t)row * N + col] = f2bf(gelu_f(v + bv_));
        } else if constexpr (EPI == 1) {
          ((u16*)Cp)[(size_t)row * N + col] = f2bf(v + bv_);
        } else if constexpr (EPI == 2) {
          float sc = scales[(size_t)row * 16 + (col >> 5)];
          float zo = bf2f(zOld[(size_t)row * 512 + col]);
          ((u16*)Cp)[(size_t)row * N + col] = f2bf(zo * (1.f + sc) + gate * v);
        } else {
          ((float*)Cp)[(size_t)row * N + col] = v + bv_;
        }
      }
    }
  }
}

// ---------------- legacy enc1 (A=f32, register-staged dbuf) — ws fallback ----------
__global__ __launch_bounds__(256, 2)
void gemm_enc1_legacy(const float* __restrict__ Af, const u16* __restrict__ Bw,
                      const float* __restrict__ bias, u16* __restrict__ Cp,
                      int M, int N, int K)
{
  __shared__ u16 At[2][128 * 64];
  __shared__ u16 Bt[2][64 * 64];
  const int tid = threadIdx.x;
  const int lane = tid & 63;
  const int wid = tid >> 6;
  const int nx = N >> 6;
  const int ny = M >> 7;
  const int d = blockIdx.x;
  const int xcd = d & 7;
  const int seq = d >> 3;
  const int by = xcd * (ny >> 3) + seq / nx;
  const int bx = seq - (seq / nx) * nx;
  const int m0 = by << 7;
  const int n0 = bx << 6;
  const int wr = wid >> 1, wc = wid & 1;
  const int r16 = lane & 15;
  const int kg = (lane >> 4) << 3;
  const int sw = (r16 & 7) << 4;
  const int NT = K >> 6;
  f32x4 acc[4][2] = {};
  float4 aA[8];

  #pragma unroll
  for (int it = 0; it < 4; ++it) {
    int c = it * 256 + tid;
    int row = c >> 3;
    int cbyte = (c & 7) << 4;
    const float* src = Af + (size_t)(m0 + row) * K + ((c & 7) << 3);
    float4 v0 = *(const float4*)src;
    float4 v1 = *(const float4*)(src + 4);
    u16x8 u;
    u[0] = f2bf(v0.x); u[1] = f2bf(v0.y); u[2] = f2bf(v0.z); u[3] = f2bf(v0.w);
    u[4] = f2bf(v1.x); u[5] = f2bf(v1.y); u[6] = f2bf(v1.z); u[7] = f2bf(v1.w);
    *(u16x8*)((char*)At[0] + row * 128 + (cbyte ^ ((row & 7) << 4))) = u;
  }
  #pragma unroll
  for (int it = 0; it < 2; ++it) {
    int c = ((it * 4 + wid) << 6) + lane;
    int row = c >> 3;
    int cbyte = (c & 7) << 4;
    const char* g = (const char*)(Bw + (size_t)(n0 + row) * K) + (cbyte ^ ((row & 7) << 4));
    gload_lds16(g, (char*)Bt[0] + ((it * 4 + wid) << 10));
  }
  __syncthreads();

  for (int kt = 0; kt < NT; ++kt) {
    const int cur = kt & 1;
    const bool hasNext = (kt + 1) < NT;
    if (hasNext) {
      const int kn = (kt + 1) << 6;
      #pragma unroll
      for (int it = 0; it < 4; ++it) {
        int c = it * 256 + tid;
        int row = c >> 3;
        const float* src = Af + (size_t)(m0 + row) * K + kn + ((c & 7) << 3);
        aA[it * 2]     = *(const float4*)src;
        aA[it * 2 + 1] = *(const float4*)(src + 4);
      }
      #pragma unroll
      for (int it = 0; it < 2; ++it) {
        int c = ((it * 4 + wid) << 6) + lane;
        int row = c >> 3;
        int cbyte = (c & 7) << 4;
        const char* g = (const char*)(Bw + (size_t)(n0 + row) * K + kn) + (cbyte ^ ((row & 7) << 4));
        gload_lds16(g, (char*)Bt[cur ^ 1] + ((it * 4 + wid) << 10));
      }
    }
    #pragma unroll
    for (int kk = 0; kk < 64; kk += 32) {
      const int kb = ((kk + kg) << 1) ^ sw;
      bf16x8 av[4], bv[2];
      #pragma unroll
      for (int m = 0; m < 4; ++m)
        av[m] = *(const bf16x8*)((const char*)At[cur] + (wr * 64 + m * 16 + r16) * 128 + kb);
      #pragma unroll
      for (int n = 0; n < 2; ++n)
        bv[n] = *(const bf16x8*)((const char*)Bt[cur] + (wc * 32 + n * 16 + r16) * 128 + kb);
      #pragma unroll
      for (int m = 0; m < 4; ++m)
        #pragma unroll
        for (int n = 0; n < 2; ++n)
          acc[m][n] = MFMA(av[m], bv[n], acc[m][n]);
    }
    if (hasNext) {
      #pragma unroll
      for (int it = 0; it < 4; ++it) {
        int c = it * 256 + tid;
        int row = c >> 3;
        int cbyte = (c & 7) << 4;
        float4 v0 = aA[it * 2], v1 = aA[it * 2 + 1];
        u16x8 u;
        u[0] = f2bf(v0.x); u[1] = f2bf(v0.y); u[2] = f2bf(v0.z); u[3] = f2bf(v0.w);
        u[4] = f2bf(v1.x); u[5] = f2bf(v1.y); u[6] = f2bf(v1.z); u[7] = f2bf(v1.w);
        *(u16x8*)((char*)At[cur ^ 1] + row * 128 + (cbyte ^ ((row & 7) << 4))) = u;
      }
    }
    __syncthreads();
  }

  const int colBase = n0 + wc * 32 + r16;
  const int rowBase = m0 + wr * 64 + ((lane >> 4) << 2);
  #pragma unroll
  for (int n = 0; n < 2; ++n) {
    int col = colBase + n * 16;
    float bv_ = bias[col];
    #pragma unroll
    for (int m = 0; m < 4; ++m)
      #pragma unroll
      for (int r = 0; r < 4; ++r) {
        int row = rowBase + m * 16 + r;
        Cp[(size_t)row * N + col] = f2bf(gelu_f(acc[m][n][r] + bv_));
      }
  }
}

// ---------------- lane-per-row norm MLP (no cross-lane ops) ----------------
// Block: 256 threads = 256 rows. Phase A: coalesced bundle norms -> LDS.
// Phase B: lane owns one row; 16->64->64->16 MLP in registers, weights via
// uniform (scalar) loads. h2[64] statically indexed (j-loops fully unrolled).
__global__ __launch_bounds__(256, 2)
void norm_mlp2(const u16* __restrict__ z,
               const float* __restrict__ w1, const float* __restrict__ b1,
               const float* __restrict__ w2, const float* __restrict__ b2,
               const float* __restrict__ w3, float* __restrict__ scales)
{
  __shared__ float nrm[256][17];             // padded: conflict-light
  const int tid = threadIdx.x;
  const size_t base = (size_t)blockIdx.x << 8;   // 256 rows/block

  // ---- Phase A: bundle norms, fully coalesced (64B per lane, consecutive) ----
  #pragma unroll
  for (int p = 0; p < 16; ++p) {
    const int C = (p << 8) + tid;            // 64B-chunk id within block's strip
    const int r = C >> 4, b = C & 15;
    const u16* zp = z + ((base + r) << 9) + (b << 5);
    float ss = 0.f;
    #pragma unroll
    for (int q = 0; q < 4; ++q) {
      u16x8 v = *(const u16x8*)(zp + q * 8);
      #pragma unroll
      for (int j = 0; j < 8; ++j) { float f = bf2f(v[j]); ss += f * f; }
    }
    nrm[r][b] = sqrtf(ss) + 1e-8f;
  }
  __syncthreads();

  // ---- Phase B: lane-per-row MLP ----
  float nr[16];
  #pragma unroll
  for (int i = 0; i < 16; ++i) nr[i] = nrm[tid][i];

  float h2[64];
  #pragma unroll
  for (int j = 0; j < 64; ++j) h2[j] = b2[j];

  for (int kt = 0; kt < 4; ++kt) {           // rolled: keeps code icache-sized
    float h1t[16];
    #pragma unroll
    for (int k16 = 0; k16 < 16; ++k16) {
      const int k = (kt << 4) + k16;
      float t = b1[k];
      #pragma unroll
      for (int i = 0; i < 16; ++i) t += nr[i] * w1[k * 16 + i];
      h1t[k16] = gelu_f(t);
    }
    const float* w2t = w2 + (kt << 4);
    #pragma unroll
    for (int j = 0; j < 64; ++j) {           // fully unrolled: h2[j] stays in regs
      float s = 0.f;
      #pragma unroll
      for (int k16 = 0; k16 < 16; ++k16) s += h1t[k16] * w2t[j * 64 + k16];
      h2[j] += s;
    }
  }
  #pragma unroll
  for (int j = 0; j < 64; ++j) h2[j] = gelu_f(h2[j]);

  float* srow = scales + ((base + tid) << 4);
  #pragma unroll
  for (int b = 0; b < 16; ++b) {
    float s = 0.f;
    #pragma unroll
    for (int k = 0; k < 64; ++k) s += h2[k] * w3[b * 64 + k];
    s = (s > 20.f) ? s : log1pf(expf(s));    // softplus
    srow[b] = s;
  }
}

// ---------------- launch ----------------
extern "C" void kernel_launch(void* const* d_in, const int* in_sizes, int n_in,
                              void* d_out, int out_size, void* d_ws, size_t ws_size,
                              hipStream_t stream)
{
  (void)in_sizes; (void)n_in; (void)out_size;
  const float* x      = (const float*)d_in[0];
  const float* enc_w1 = (const float*)d_in[1];
  const float* enc_b1 = (const float*)d_in[2];
  const float* enc_w2 = (const float*)d_in[3];
  const float* enc_b2 = (const float*)d_in[4];
  const float* enc_w3 = (const float*)d_in[5];
  const float* enc_b3 = (const float*)d_in[6];
  const float* mlp1_w = (const float*)d_in[7];
  const float* mlp1_b = (const float*)d_in[8];
  const float* mlp2_w = (const float*)d_in[9];
  const float* mlp2_b = (const float*)d_in[10];
  const float* mlp3_w = (const float*)d_in[11];
  const float* mix_w  = (const float*)d_in[12];
  const float* gate_b = (const float*)d_in[13];
  const float* dec_w1 = (const float*)d_in[14];
  const float* dec_b1 = (const float*)d_in[15];
  const float* dec_w2 = (const float*)d_in[16];
  const float* dec_b2 = (const float*)d_in[17];
  const float* dec_w3 = (const float*)d_in[18];
  const float* dec_b3 = (const float*)d_in[19];

  char* ws = (char*)d_ws;
  const int M = 65536;
  dim3 blk(256);
  const int g512  = 8  * 512;   // (N/64)*(M/128), XCD-swizzled 1-D
  const int g1024 = 16 * 512;

  // big layout: xb 128MB | zA 64MB | (zB overlays xb) | scales | weights
  const bool bigWs = (ws_size >= 211812352ULL);
  u16 *xb, *zA, *zB;
  float* scales;
  u16* wBase;
  if (bigWs) {
    xb     = (u16*)ws;
    zA     = (u16*)(ws + 134217728ULL);
    zB     = (u16*)ws;                       // overlays xb (dead after enc1)
    scales = (float*)(ws + 201326592ULL);
    wBase  = (u16*)(ws + 205520896ULL);
  } else {
    xb     = nullptr;
    zA     = (u16*)ws;
    zB     = (u16*)(ws + 67108864ULL);
    scales = (float*)(ws + 134217728ULL);
    wBase  = (u16*)(ws + 138412032ULL);
  }
  u16* wE1 = wBase;
  u16* wE2 = wE1 + 524288;
  u16* wE3 = wE2 + 262144;
  u16* wD1 = wE3 + 262144;
  u16* wD2 = wD1 + 262144;
  u16* wD3 = wD2 + 262144;
  u16* wMix = wD3 + 524288;

  cvt_all<<<512, 256, 0, stream>>>(enc_w1, enc_w2, enc_w3, dec_w1, dec_w2, dec_w3,
                                   mix_w, wBase);

  // encoder
  if (bigWs) {
    cvt_x<<<2048, 256, 0, stream>>>(x, xb);
    gemm_p<0><<<g512, blk, 0, stream>>>(xb, wE1, enc_b1, zA, nullptr, nullptr, nullptr, M, 512, 1024);
  } else {
    gemm_enc1_legacy<<<g512, blk, 0, stream>>>(x, wE1, enc_b1, zA, M, 512, 1024);
  }
  gemm_p<0><<<g512, blk, 0, stream>>>(zA, wE2, enc_b2, zB, nullptr, nullptr, nullptr, M, 512, 512);
  gemm_p<1><<<g512, blk, 0, stream>>>(zB, wE3, enc_b3, zA, nullptr, nullptr, nullptr, M, 512, 512);

  // latent layers
  u16* cur = zA;
  u16* nxt = zB;
  for (int l = 0; l < 4; ++l) {
    norm_mlp2<<<256, blk, 0, stream>>>(cur, mlp1_w + l * 1024, mlp1_b + l * 64,
                                       mlp2_w + l * 4096, mlp2_b + l * 64,
                                       mlp3_w + l * 1024, scales);
    gemm_p<2><<<g512, blk, 0, stream>>>(cur, wMix + (size_t)l * 262144, nullptr, nxt,
                                        cur, scales, gate_b + l * 16, M, 512, 512);
    u16* t = cur; cur = nxt; nxt = t;
  }

  // decoder
  gemm_p<0><<<g512, blk, 0, stream>>>(cur, wD1, dec_b1, nxt, nullptr, nullptr, nullptr, M, 512, 512);
  { u16* t = cur; cur = nxt; nxt = t; }
  gemm_p<0><<<g512, blk, 0, stream>>>(cur, wD2, dec_b2, nxt, nullptr, nullptr, nullptr, M, 512, 512);
  { u16* t = cur; cur = nxt; nxt = t; }
  gemm_p<3><<<g1024, blk, 0, stream>>>(cur, wD3, dec_b3, d_out, nullptr, nullptr, nullptr, M, 1024, 512);
}

// Round 14
// 1388.239 us; speedup vs baseline: 1.3456x; 1.0144x over previous
//
#include <hip/hip_runtime.h>
#include <hip/hip_bf16.h>

typedef float f32x4 __attribute__((ext_vector_type(4)));
typedef __bf16 bf16x8 __attribute__((ext_vector_type(8)));
typedef unsigned short u16x8 __attribute__((ext_vector_type(8)));
typedef unsigned short u16;

__device__ __forceinline__ u16 f2bf(float f) {
  __bf16 h = (__bf16)f;                       // native cvt (RNE)
  return __builtin_bit_cast(u16, h);
}
__device__ __forceinline__ float bf2f(u16 s) {
  return __uint_as_float(((unsigned int)s) << 16);
}
__device__ __forceinline__ float gelu_f(float x) {
  return 0.5f * x * (1.0f + erff(x * 0.70710678118654752f)); // erf GELU
}
__device__ __forceinline__ void gload_lds16(const void* g, void* l) {
  __builtin_amdgcn_global_load_lds((const __attribute__((address_space(1))) void*)g,
                                   (__attribute__((address_space(3))) void*)l, 16, 0, 0);
}
#define MFMA(a, b, c) __builtin_amdgcn_mfma_f32_16x16x32_bf16((a), (b), (c), 0, 0, 0)
#define BARRIER_PINNED() do { \
    __builtin_amdgcn_s_barrier(); \
    asm volatile("" ::: "memory"); \
    __builtin_amdgcn_sched_barrier(0); \
  } while (0)

// ---------------- weight conversion ----------------
__global__ void cvt_all(const float* __restrict__ e1, const float* __restrict__ e2,
                        const float* __restrict__ e3, const float* __restrict__ d1,
                        const float* __restrict__ d2, const float* __restrict__ d3,
                        const float* __restrict__ mx, u16* __restrict__ dst)
{
  int i = blockIdx.x * blockDim.x + threadIdx.x;
  int stride = gridDim.x * blockDim.x;
  for (; i < 3145728; i += stride) {
    float v;
    if (i < 524288)        v = e1[i];
    else if (i < 786432)   v = e2[i - 524288];
    else if (i < 1048576)  v = e3[i - 786432];
    else if (i < 1310720)  v = d1[i - 1048576];
    else if (i < 1572864)  v = d2[i - 1310720];
    else if (i < 2097152)  v = d3[i - 1572864];
    else {
      // mix_w [L,16,16,32,32] (l,bi,j,e,d) -> W[l][o=bi*32+e][k=j*32+d]
      int j = i - 2097152;
      int l = j >> 18, rem = j & 262143;
      int o = rem >> 9, k = rem & 511;
      int bi = o >> 5, e = o & 31, jj = k >> 5, dd = k & 31;
      v = mx[(((l * 16 + bi) * 16 + jj) * 32 + e) * 32 + dd];
    }
    dst[i] = f2bf(v);
  }
}

// x f32 -> bf16 (vectorized)
__global__ void cvt_x(const float* __restrict__ s, u16* __restrict__ d) {
  int i = blockIdx.x * blockDim.x + threadIdx.x;
  int stride = gridDim.x * blockDim.x;
  for (; i < 8388608; i += stride) {
    float4 v0 = *(const float4*)(s + (size_t)i * 8);
    float4 v1 = *(const float4*)(s + (size_t)i * 8 + 4);
    u16x8 u;
    u[0] = f2bf(v0.x); u[1] = f2bf(v0.y); u[2] = f2bf(v0.z); u[3] = f2bf(v0.w);
    u[4] = f2bf(v1.x); u[5] = f2bf(v1.y); u[6] = f2bf(v1.z); u[7] = f2bf(v1.w);
    *(u16x8*)(d + (size_t)i * 8) = u;
  }
}

// ================= A-panel-resident GEMM (K=512 fixed) =================
// Block = 512 thr (8 waves), owns 128 rows for ALL N. LDS: A panel 128x512 bf16
// (128KB, staged once) + B dbuf 2 x [128x64] (16KB each) = 163840 B (full pool,
// 1 block/CU). Waves 2(M)x4(N), wave tile 64x32, acc[4][2]=32 VGPR.
// Per K-step: vmcnt(0) [B issued a full K-step ago -> ~0 wait] -> barrier ->
// issue next B tile -> 16 MFMA. B is L2-resident (512KB weights chip-wide).
// EPI: 0 bias+GELU->bf16 ; 1 bias->bf16 ; 2 latent combine->bf16 ; 3 bias->f32
template<int EPI>
__global__ __launch_bounds__(512, 2)
void gemm_panel(const u16* __restrict__ A, const u16* __restrict__ Bw,
                const float* __restrict__ bias, void* __restrict__ Cp,
                const float* __restrict__ scales, const float* __restrict__ gateBias,
                int N)
{
  extern __shared__ char smem[];
  char* Apan = smem;                       // 131072 B; B buffers at +131072/+147456

  const int tid = threadIdx.x;
  const int lane = tid & 63;
  const int wid = tid >> 6;
  const int m0 = blockIdx.x << 7;

  const int wr = wid >> 2;                 // 0..1 (M half)
  const int wc = wid & 3;                  // 0..3 (N quarter of 128-tile)
  const int r16 = lane & 15;
  const int kg = (lane >> 4) << 3;         // elem offset 0,8,16,24
  const int sw = (r16 & 7) << 4;

  // ---- prologue: stage A panel (8192 chunks) + B tile 0 ----
  #pragma unroll
  for (int it = 0; it < 16; ++it) {
    int c = ((it * 8 + wid) << 6) + lane;  // 16B chunk id in [0,8192)
    int row = c >> 6;                      // 64 chunks per 1024B row
    int cb = (c & 63) << 4;
    const char* g = (const char*)(A + ((size_t)(m0 + row) << 9)) + (cb ^ ((row & 7) << 4));
    gload_lds16(g, Apan + ((it * 8 + wid) << 10));
  }
  #pragma unroll
  for (int it = 0; it < 2; ++it) {
    int c = ((it * 8 + wid) << 6) + lane;  // [0,1024): B tile 128 rows x 8 chunks
    int row = c >> 3;
    int cb = (c & 7) << 4;
    const char* g = (const char*)(Bw + ((size_t)row << 9)) + (cb ^ ((row & 7) << 4));
    gload_lds16(g, smem + 131072 + ((it * 8 + wid) << 10));
  }

  const int nN = N >> 7;                   // N-tiles of 128
  const int S = nN << 3;                   // total K-steps (8 per N-tile)
  f32x4 acc[4][2] = {};

  for (int s = 0; s < S; ++s) {
    const int kt = s & 7;
    const int nt = s >> 3;

    asm volatile("s_waitcnt vmcnt(0)" ::: "memory");   // B(s) landed (issued ~1 K-step ago)
    BARRIER_PINNED();

    if (s + 1 < S) {                       // issue B(s+1) into the other buffer
      const int ktn = (s + 1) & 7;
      const int ntn = (s + 1) >> 3;
      char* dst = smem + 131072 + (((s + 1) & 1) << 14);
      #pragma unroll
      for (int it = 0; it < 2; ++it) {
        int c = ((it * 8 + wid) << 6) + lane;
        int row = c >> 3;
        int cb = (c & 7) << 4;
        const char* g = (const char*)(Bw + ((size_t)((ntn << 7) + row) << 9) + (ktn << 6))
                        + (cb ^ ((row & 7) << 4));
        gload_lds16(g, dst + ((it * 8 + wid) << 10));
      }
    }

    // ---- compute K-step kt of N-tile nt ----
    const char* Bc = smem + 131072 + ((s & 1) << 14);
    #pragma unroll
    for (int kk = 0; kk < 64; kk += 32) {
      const int kbA = ((kt << 7) + ((kk + kg) << 1)) ^ sw;
      const int kbB = ((kk + kg) << 1) ^ sw;
      bf16x8 av[4], bv[2];
      #pragma unroll
      for (int m = 0; m < 4; ++m)
        av[m] = *(const bf16x8*)(Apan + ((wr * 64 + m * 16 + r16) << 10) + kbA);
      #pragma unroll
      for (int n = 0; n < 2; ++n)
        bv[n] = *(const bf16x8*)(Bc + ((wc * 32 + n * 16 + r16) << 7) + kbB);
      __builtin_amdgcn_s_setprio(1);
      #pragma unroll
      for (int m = 0; m < 4; ++m)
        #pragma unroll
        for (int n = 0; n < 2; ++n)
          acc[m][n] = MFMA(av[m], bv[n], acc[m][n]);
      __builtin_amdgcn_s_setprio(0);
    }

    // ---- per-N-tile epilogue ----
    if (kt == 7) {
      const int colBase = (nt << 7) + wc * 32 + r16;
      const int rowOff = wr * 64 + ((lane >> 4) << 2);
      #pragma unroll
      for (int n = 0; n < 2; ++n) {
        const int col = colBase + n * 16;
        float bv_ = 0.f, gate = 0.f;
        if constexpr (EPI == 0 || EPI == 1 || EPI == 3) bv_ = bias[col];
        if constexpr (EPI == 2) gate = 1.f / (1.f + expf(-gateBias[col >> 5]));
        #pragma unroll
        for (int m = 0; m < 4; ++m) {
          #pragma unroll
          for (int r = 0; r < 4; ++r) {
            const int rloc = rowOff + m * 16 + r;
            const int row = m0 + rloc;
            float v = acc[m][n][r];
            if constexpr (EPI == 0) {
              ((u16*)Cp)[(size_t)row * N + col] = f2bf(gelu_f(v + bv_));
            } else if constexpr (EPI == 1) {
              ((u16*)Cp)[(size_t)row * N + col] = f2bf(v + bv_);
            } else if constexpr (EPI == 2) {
              float sc = scales[(size_t)row * 16 + (col >> 5)];
              // zOld straight from the LDS A panel
              float zo = bf2f(*(const u16*)(Apan + ((size_t)rloc << 10) + (((col << 1)) ^ ((rloc & 7) << 4))));
              ((u16*)Cp)[(size_t)row * N + col] = f2bf(zo * (1.f + sc) + gate * v);
            } else {
              ((float*)Cp)[(size_t)row * N + col] = v + bv_;
            }
          }
        }
      }
      #pragma unroll
      for (int m = 0; m < 4; ++m)
        #pragma unroll
        for (int n = 0; n < 2; ++n)
          acc[m][n] = f32x4{0.f, 0.f, 0.f, 0.f};
    }
  }
}

// ---------------- pipelined GEMM for enc1 (K=1024; panel doesn't fit) ----------
__device__ __forceinline__ void stage_AB(const u16* __restrict__ Ab,
                                         const u16* __restrict__ Bb, int K,
                                         u16* At, u16* Bt, int wid, int lane)
{
  #pragma unroll
  for (int it = 0; it < 4; ++it) {
    int c = ((it * 4 + wid) << 6) + lane;
    int row = c >> 3;
    int cb = (c & 7) << 4;
    const char* g = (const char*)(Ab + (size_t)row * K) + (cb ^ ((row & 7) << 4));
    gload_lds16(g, (char*)At + ((it * 4 + wid) << 10));
  }
  #pragma unroll
  for (int it = 0; it < 2; ++it) {
    int c = ((it * 4 + wid) << 6) + lane;
    int row = c >> 3;
    int cb = (c & 7) << 4;
    const char* g = (const char*)(Bb + (size_t)row * K) + (cb ^ ((row & 7) << 4));
    gload_lds16(g, (char*)Bt + ((it * 4 + wid) << 10));
  }
}

__global__ __launch_bounds__(256, 2)
void gemm_p0(const u16* __restrict__ A, const u16* __restrict__ Bw,
             const float* __restrict__ bias, u16* __restrict__ Cp, int M, int N, int K)
{
  __shared__ u16 At[3][128 * 64];
  __shared__ u16 Bt[3][64 * 64];
  const int tid = threadIdx.x;
  const int lane = tid & 63;
  const int wid = tid >> 6;

  const int nx = N >> 6;
  const int ny = M >> 7;
  const int d = blockIdx.x;
  const int xcd = d & 7;
  const int seq = d >> 3;
  const int by = xcd * (ny >> 3) + seq / nx;
  const int bx = seq - (seq / nx) * nx;
  const int m0 = by << 7;
  const int n0 = bx << 6;

  const int wr = wid >> 1, wc = wid & 1;
  const int r16 = lane & 15;
  const int kg = (lane >> 4) << 3;
  const int sw = (r16 & 7) << 4;

  const u16* Ab = A + (size_t)m0 * K;
  const u16* Bb = Bw + (size_t)n0 * K;
  const int NT = K >> 6;

  f32x4 acc[4][2] = {};

  stage_AB(Ab,      Bb,      K, At[0], Bt[0], wid, lane);
  stage_AB(Ab + 64, Bb + 64, K, At[1], Bt[1], wid, lane);

  int cb = 0, ib = 2;
  for (int kt = 0; kt < NT; ++kt) {
    if (kt + 1 < NT) { asm volatile("s_waitcnt vmcnt(6)" ::: "memory"); }
    else             { asm volatile("s_waitcnt vmcnt(0)" ::: "memory"); }
    BARRIER_PINNED();

    if (kt + 2 < NT) {
      stage_AB(Ab + ((kt + 2) << 6), Bb + ((kt + 2) << 6), K, At[ib], Bt[ib], wid, lane);
      ib = (ib == 2) ? 0 : ib + 1;
    }

    const char* Ac = (const char*)At[cb];
    const char* Bc = (const char*)Bt[cb];
    #pragma unroll
    for (int kk = 0; kk < 64; kk += 32) {
      const int kb = ((kk + kg) << 1) ^ sw;
      bf16x8 av[4], bv[2];
      #pragma unroll
      for (int m = 0; m < 4; ++m)
        av[m] = *(const bf16x8*)(Ac + (wr * 64 + m * 16 + r16) * 128 + kb);
      #pragma unroll
      for (int n = 0; n < 2; ++n)
        bv[n] = *(const bf16x8*)(Bc + (wc * 32 + n * 16 + r16) * 128 + kb);
      __builtin_amdgcn_s_setprio(1);
      #pragma unroll
      for (int m = 0; m < 4; ++m)
        #pragma unroll
        for (int n = 0; n < 2; ++n)
          acc[m][n] = MFMA(av[m], bv[n], acc[m][n]);
      __builtin_amdgcn_s_setprio(0);
    }
    cb = (cb == 2) ? 0 : cb + 1;
  }

  const int colBase = n0 + wc * 32 + r16;
  const int rowBase = m0 + wr * 64 + ((lane >> 4) << 2);
  #pragma unroll
  for (int n = 0; n < 2; ++n) {
    int col = colBase + n * 16;
    float bv_ = bias[col];
    #pragma unroll
    for (int m = 0; m < 4; ++m)
      #pragma unroll
      for (int r = 0; r < 4; ++r) {
        int row = rowBase + m * 16 + r;
        Cp[(size_t)row * N + col] = f2bf(gelu_f(acc[m][n][r] + bv_));
      }
  }
}

// ---------------- lane-per-row norm MLP ----------------
__global__ __launch_bounds__(256, 2)
void norm_mlp2(const u16* __restrict__ z,
               const float* __restrict__ w1, const float* __restrict__ b1,
               const float* __restrict__ w2, const float* __restrict__ b2,
               const float* __restrict__ w3, float* __restrict__ scales)
{
  __shared__ float nrm[256][17];
  const int tid = threadIdx.x;
  const size_t base = (size_t)blockIdx.x << 8;

  #pragma unroll
  for (int p = 0; p < 16; ++p) {
    const int C = (p << 8) + tid;
    const int r = C >> 4, b = C & 15;
    const u16* zp = z + ((base + r) << 9) + (b << 5);
    float ss = 0.f;
    #pragma unroll
    for (int q = 0; q < 4; ++q) {
      u16x8 v = *(const u16x8*)(zp + q * 8);
      #pragma unroll
      for (int j = 0; j < 8; ++j) { float f = bf2f(v[j]); ss += f * f; }
    }
    nrm[r][b] = sqrtf(ss) + 1e-8f;
  }
  __syncthreads();

  float nr[16];
  #pragma unroll
  for (int i = 0; i < 16; ++i) nr[i] = nrm[tid][i];

  float h2[64];
  #pragma unroll
  for (int j = 0; j < 64; ++j) h2[j] = b2[j];

  for (int kt = 0; kt < 4; ++kt) {
    float h1t[16];
    #pragma unroll
    for (int k16 = 0; k16 < 16; ++k16) {
      const int k = (kt << 4) + k16;
      float t = b1[k];
      #pragma unroll
      for (int i = 0; i < 16; ++i) t += nr[i] * w1[k * 16 + i];
      h1t[k16] = gelu_f(t);
    }
    const float* w2t = w2 + (kt << 4);
    #pragma unroll
    for (int j = 0; j < 64; ++j) {
      float s = 0.f;
      #pragma unroll
      for (int k16 = 0; k16 < 16; ++k16) s += h1t[k16] * w2t[j * 64 + k16];
      h2[j] += s;
    }
  }
  #pragma unroll
  for (int j = 0; j < 64; ++j) h2[j] = gelu_f(h2[j]);

  float* srow = scales + ((base + tid) << 4);
  #pragma unroll
  for (int b = 0; b < 16; ++b) {
    float s = 0.f;
    #pragma unroll
    for (int k = 0; k < 64; ++k) s += h2[k] * w3[b * 64 + k];
    s = (s > 20.f) ? s : log1pf(expf(s));
    srow[b] = s;
  }
}

// ---------------- launch ----------------
#define PANEL_SMEM 163840

extern "C" void kernel_launch(void* const* d_in, const int* in_sizes, int n_in,
                              void* d_out, int out_size, void* d_ws, size_t ws_size,
                              hipStream_t stream)
{
  (void)in_sizes; (void)n_in; (void)out_size; (void)ws_size;
  const float* x      = (const float*)d_in[0];
  const float* enc_w1 = (const float*)d_in[1];
  const float* enc_b1 = (const float*)d_in[2];
  const float* enc_w2 = (const float*)d_in[3];
  const float* enc_b2 = (const float*)d_in[4];
  const float* enc_w3 = (const float*)d_in[5];
  const float* enc_b3 = (const float*)d_in[6];
  const float* mlp1_w = (const float*)d_in[7];
  const float* mlp1_b = (const float*)d_in[8];
  const float* mlp2_w = (const float*)d_in[9];
  const float* mlp2_b = (const float*)d_in[10];
  const float* mlp3_w = (const float*)d_in[11];
  const float* mix_w  = (const float*)d_in[12];
  const float* gate_b = (const float*)d_in[13];
  const float* dec_w1 = (const float*)d_in[14];
  const float* dec_b1 = (const float*)d_in[15];
  const float* dec_w2 = (const float*)d_in[16];
  const float* dec_b2 = (const float*)d_in[17];
  const float* dec_w3 = (const float*)d_in[18];
  const float* dec_b3 = (const float*)d_in[19];

  char* ws = (char*)d_ws;
  const int M = 65536;

  // ws: xb 128MB | zA 64MB | (zB overlays xb) | scales 4MB | weights 6MB
  u16*   xb     = (u16*)ws;
  u16*   zA     = (u16*)(ws + 134217728ULL);
  u16*   zB     = (u16*)ws;                 // overlays xb (dead after enc1)
  float* scales = (float*)(ws + 201326592ULL);
  u16*   wBase  = (u16*)(ws + 205520896ULL);
  u16* wE1 = wBase;
  u16* wE2 = wE1 + 524288;
  u16* wE3 = wE2 + 262144;
  u16* wD1 = wE3 + 262144;
  u16* wD2 = wD1 + 262144;
  u16* wD3 = wD2 + 262144;
  u16* wMix = wD3 + 524288;

  hipError_t e;
  e = hipFuncSetAttribute(reinterpret_cast<const void*>(&gemm_panel<0>),
                          hipFuncAttributeMaxDynamicSharedMemorySize, PANEL_SMEM);
  e = hipFuncSetAttribute(reinterpret_cast<const void*>(&gemm_panel<1>),
                          hipFuncAttributeMaxDynamicSharedMemorySize, PANEL_SMEM);
  e = hipFuncSetAttribute(reinterpret_cast<const void*>(&gemm_panel<2>),
                          hipFuncAttributeMaxDynamicSharedMemorySize, PANEL_SMEM);
  e = hipFuncSetAttribute(reinterpret_cast<const void*>(&gemm_panel<3>),
                          hipFuncAttributeMaxDynamicSharedMemorySize, PANEL_SMEM);
  (void)e;

  cvt_all<<<512, 256, 0, stream>>>(enc_w1, enc_w2, enc_w3, dec_w1, dec_w2, dec_w3,
                                   mix_w, wBase);

  dim3 pblk(512);
  const int pgrid = 512;                    // M/128 blocks, A-panel resident

  // encoder
  cvt_x<<<2048, 256, 0, stream>>>(x, xb);
  gemm_p0<<<8 * 512, dim3(256), 0, stream>>>(xb, wE1, enc_b1, zA, M, 512, 1024);
  gemm_panel<0><<<pgrid, pblk, PANEL_SMEM, stream>>>(zA, wE2, enc_b2, zB, nullptr, nullptr, 512);
  gemm_panel<1><<<pgrid, pblk, PANEL_SMEM, stream>>>(zB, wE3, enc_b3, zA, nullptr, nullptr, 512);

  // latent layers
  u16* cur = zA;
  u16* nxt = zB;
  for (int l = 0; l < 4; ++l) {
    norm_mlp2<<<256, dim3(256), 0, stream>>>(cur, mlp1_w + l * 1024, mlp1_b + l * 64,
                                             mlp2_w + l * 4096, mlp2_b + l * 64,
                                             mlp3_w + l * 1024, scales);
    gemm_panel<2><<<pgrid, pblk, PANEL_SMEM, stream>>>(cur, wMix + (size_t)l * 262144,
                                                       nullptr, nxt, scales, gate_b + l * 16, 512);
    u16* t = cur; cur = nxt; nxt = t;
  }

  // decoder
  gemm_panel<0><<<pgrid, pblk, PANEL_SMEM, stream>>>(cur, wD1, dec_b1, nxt, nullptr, nullptr, 512);
  { u16* t = cur; cur = nxt; nxt = t; }
  gemm_panel<0><<<pgrid, pblk, PANEL_SMEM, stream>>>(cur, wD2, dec_b2, nxt, nullptr, nullptr, 512);
  { u16* t = cur; cur = nxt; nxt = t; }
  gemm_panel<3><<<pgrid, pblk, PANEL_SMEM, stream>>>(cur, wD3, dec_b3, d_out, nullptr, nullptr, 1024);
}